// Round 8
// baseline (185.185 us; speedup 1.0000x reference)
//
#include <hip/hip_runtime.h>

// Problem constants (fixed by setup_inputs)
#define BB 8
#define CIN 64
#define COUT 64
#define NN 2048
#define TT 13
#define KTT 3
#define LL 11
#define CL 704                         // COUT*LL
#define HP_SIZE 11534336LL             // B*COUT*N*L

// GEMM tiling
#define BM 176                         // 11 m-frags of 16
#define BN 256                         // 4 q-waves x 64 q
#define A_TILE 5632                    // 4kc x 176 x 8 fp16 per k-tile(32)

// ws layout (bytes): fbuf 65536 | maxf 32 | tab4 262144 | w0pk 24576 | Apan
#define WS_TAB_OFF 65568ULL
#define WS_W0PK_OFF 327712ULL
#define WS_APAN_OFF 352288ULL

typedef _Float16 f16;
typedef __attribute__((ext_vector_type(8))) _Float16 f16x8;
typedef __attribute__((ext_vector_type(2))) _Float16 f16x2;
typedef __attribute__((ext_vector_type(4))) float f32x4;

__device__ __forceinline__ unsigned int pk16(float a, float b) {
  f16 ha = (f16)a, hb = (f16)b;                    // RTN converts
  unsigned short ua = __builtin_bit_cast(unsigned short, ha);
  unsigned short ub = __builtin_bit_cast(unsigned short, hb);
  return (unsigned int)ua | ((unsigned int)ub << 16);
}
__device__ __forceinline__ f16x2 as_h2(unsigned int u) {
  return __builtin_bit_cast(f16x2, u);
}
__device__ __forceinline__ void gl_lds16(const f16* g, f16* l) {
  __builtin_amdgcn_global_load_lds(
      (const __attribute__((address_space(1))) unsigned int*)g,
      (__attribute__((address_space(3))) unsigned int*)l, 16, 0, 0);
}

// ---------------------------------------------------------------------------
// Kernel 0: pack w0 into ci-pair v2f16 form, once. w0pk_g[(cip*3+kt)*64+c].
// ---------------------------------------------------------------------------
__global__ __launch_bounds__(256) void k_pack(const float* __restrict__ w0,
                                              unsigned int* __restrict__ w0pk_g) {
  int tid = blockIdx.x * 256 + threadIdx.x;        // 6144 total
  int c = tid & 63, r = tid >> 6;                  // r = cip*3+kt, 0..95
  int kt = r % 3, cip = r / 3;
  float ev = w0[c * 192 + cip * 6 + kt];
  float od = w0[c * 192 + cip * 6 + 3 + kt];
  w0pk_g[r * 64 + c] = pk16(ev, od);
}

// ---------------------------------------------------------------------------
// Kernel 1: conv0 via v_dot2_f32_f16 (ci-pairs fp16, fp32 accum).
// Block: 512 thr = 8 waves; wave w owns n = n0+w; lane = c.
// Outputs: fp16 A panels Apan[b][ct4][ks64][kc4][176][8] + f[b,n].
// ---------------------------------------------------------------------------
__global__ __launch_bounds__(512, 4) void k_conv(
    const float* __restrict__ x, const unsigned int* __restrict__ w0pk_g,
    const float* __restrict__ b0, const float* __restrict__ w1,
    f16* __restrict__ Apan, float* __restrict__ f) {
  __shared__ unsigned int w0pk[96 * 64];       // [cip*3+kt][c]      24 KB
  __shared__ unsigned int xspk[32 * 8 * 16];   // [cip][n][t pad16]  16 KB
  __shared__ f16 As[704 * 10];                 // [m][kk8 + 2pad]    14 KB
  const int tid = threadIdx.x;
  const int b = blockIdx.x >> 8;
  const int n0 = (blockIdx.x & 255) << 3;

  // stage packed w0: coalesced, conflict-free
#pragma unroll
  for (int i = 0; i < 12; ++i) w0pk[i * 512 + tid] = w0pk_g[i * 512 + tid];

  // stage x packed: contiguous 104-dword runs per ci; task = cip*104 + rem
#pragma unroll
  for (int i = 0; i < 7; ++i) {
    int task = i * 512 + tid;                  // 3328 total
    if (task < 3328) {
      int cip = task / 104, rem = task - cip * 104;
      long long base = (long long)(b * 64 + 2 * cip) * 26624 + n0 * 13 + rem;
      float ev = x[base];
      float od = x[base + 26624];              // next ci
      int n = rem / 13, t = rem - n * 13;
      xspk[(cip * 8 + n) * 16 + t] = pk16(ev, od);   // 2-way max (free)
    }
  }
  __syncthreads();

  const int c = tid & 63, w = tid >> 6;        // lane = c, wave = local n
  float acc[11];
  const float bias = b0[c];
#pragma unroll
  for (int l = 0; l < 11; ++l) acc[l] = bias;

  for (int cip = 0; cip < 32; ++cip) {
    const unsigned int* xr = &xspk[(cip * 8 + w) * 16];   // wave-uniform
    uint4 xa = *(const uint4*)xr;
    uint4 xb = *(const uint4*)(xr + 4);
    uint4 xc = *(const uint4*)(xr + 8);
    unsigned int x13[13] = {xa.x, xa.y, xa.z, xa.w, xb.x, xb.y, xb.z, xb.w,
                            xc.x, xc.y, xc.z, xc.w, xr[12]};
    f16x2 wk0 = as_h2(w0pk[(cip * 3 + 0) * 64 + c]);
    f16x2 wk1 = as_h2(w0pk[(cip * 3 + 1) * 64 + c]);
    f16x2 wk2 = as_h2(w0pk[(cip * 3 + 2) * 64 + c]);
#pragma unroll
    for (int l = 0; l < 11; ++l) {
      acc[l] = __builtin_amdgcn_fdot2(as_h2(x13[l]), wk0, acc[l], false);
      acc[l] = __builtin_amdgcn_fdot2(as_h2(x13[l + 1]), wk1, acc[l], false);
      acc[l] = __builtin_amdgcn_fdot2(as_h2(x13[l + 2]), wk2, acc[l], false);
    }
  }

  // f reduce (lane = c)
  float p = 0.f;
#pragma unroll
  for (int l = 0; l < 11; ++l) p = fmaf(acc[l], w1[c * 11 + l], p);
#pragma unroll
  for (int off = 32; off; off >>= 1) p += __shfl_xor(p, off, 64);
  if (c == 0) f[b * 2048 + n0 + w] = p;

  // fp16 convert + LDS transpose: As[m][kk=w], row pad 10 (2-way max)
#pragma unroll
  for (int l = 0; l < 11; ++l) As[(c * 11 + l) * 10 + w] = (f16)acc[l];
  __syncthreads();

  // panel write: ks = n0>>5, kc4 = (n0>>3)&3, kk 0..7
  const int ks = n0 >> 5, kc4 = (n0 >> 3) & 3;
  const unsigned int* As32 = (const unsigned int*)As;
#pragma unroll
  for (int i = 0; i < 2; ++i) {
    int m = i * 512 + tid;
    if (m < 704) {
      uint4 v;
      v.x = As32[m * 5 + 0];
      v.y = As32[m * 5 + 1];
      v.z = As32[m * 5 + 2];
      v.w = As32[m * 5 + 3];
      int ct = m / 176, mo = m - ct * 176;
      long long base = ((long long)(b * 4 + ct) * 64 + ks) * A_TILE + kc4 * 1408 + mo * 8;
      *(uint4*)&Apan[base] = v;
    }
  }
}

// ---------------------------------------------------------------------------
// Kernel 2: per-batch max of f
// ---------------------------------------------------------------------------
__global__ __launch_bounds__(256) void k_maxf(const float* __restrict__ f,
                                              float* __restrict__ maxf) {
  const int b = blockIdx.x, tid = threadIdx.x;
  float m = -1e30f;
  for (int i = tid; i < 2048; i += 256) m = fmaxf(m, f[b * 2048 + i]);
#pragma unroll
  for (int off = 32; off; off >>= 1) m = fmaxf(m, __shfl_xor(m, off, 64));
  __shared__ float red[4];
  if ((tid & 63) == 0) red[tid >> 6] = m;
  __syncthreads();
  if (tid == 0) maxf[b] = fmaxf(fmaxf(red[0], red[1]), fmaxf(red[2], red[3]));
}

// ---------------------------------------------------------------------------
// Kernel 3: softmax row sums + exp-factor table.
// tab4[b*2048+i] = (En, E2n, Rq, Sq):
//   En = exp(f_i - mb)     E2n = exp(0.2 f_i)
//   Rq = rq * (f_i+mb>=0 ? 1 : exp(0.8(f_i+mb)))   Sq = rq * exp(0.2 f_i - m_i)
// att[n][q] = (fn+fq>=0) ? En_n*Rq_q : E2n_n*Sq_q  -- exact factorization.
// ---------------------------------------------------------------------------
__global__ __launch_bounds__(256) void k_rowsum(const float* __restrict__ f,
                                                const float* __restrict__ maxf,
                                                float4* __restrict__ tab4) {
  __shared__ float fs[2048];
  const int b = blockIdx.x >> 9;
  const int q0 = (blockIdx.x & 511) << 2;
  const int tid = threadIdx.x;
#pragma unroll
  for (int i = 0; i < 8; ++i) fs[i * 256 + tid] = f[b * 2048 + i * 256 + tid];
  __syncthreads();
  const int lane = tid & 63, wid = tid >> 6;
  const int q = q0 + wid;
  const float fq = fs[q];
  const float mb = maxf[b];
  float t = fq + mb;
  const float m = t >= 0.f ? t : 0.2f * t;     // row max of lrelu
  float sum = 0.f;
  for (int j = lane; j < 2048; j += 64) {
    float v = fq + fs[j];
    v = v >= 0.f ? v : 0.2f * v;
    sum += __expf(v - m);
  }
#pragma unroll
  for (int off = 32; off; off >>= 1) sum += __shfl_xor(sum, off, 64);
  if (lane == 0) {
    float rq = 1.0f / sum;
    float En = __expf(fq - mb);
    float E2 = __expf(0.2f * fq);
    float Rq = t >= 0.f ? rq : rq * __expf(0.8f * t);
    float Sq = rq * __expf(0.2f * fq - m);
    tab4[b * 2048 + q] = make_float4(En, E2, Rq, Sq);
  }
}

// ---------------------------------------------------------------------------
// Kernel 4: att (transposed softmax) from the exp-factor table. Write-bound.
// Block: 4 n-rows; thread owns 8 consecutive q for all 4 rows (tab reused).
// ---------------------------------------------------------------------------
__global__ __launch_bounds__(256) void k_att(const float* __restrict__ f,
                                             const float4* __restrict__ tab4,
                                             float* __restrict__ att) {
  const int b = blockIdx.x >> 9;
  const int i0 = (blockIdx.x & 511) << 2;
  const int tid = threadIdx.x;
  const float* fb = f + b * NN;
  const float4* tb = tab4 + (long long)b * NN;

  float fi[4], En[4], E2[4];
#pragma unroll
  for (int r = 0; r < 4; ++r) {
    fi[r] = fb[i0 + r];
    float4 t = tb[i0 + r];
    En[r] = t.x;
    E2[r] = t.y;
  }
  const int j0 = tid * 8;
  float4 fj0 = *(const float4*)&fb[j0];
  float4 fj1 = *(const float4*)&fb[j0 + 4];
  float fj[8] = {fj0.x, fj0.y, fj0.z, fj0.w, fj1.x, fj1.y, fj1.z, fj1.w};
  float Rq[8], Sq[8];
#pragma unroll
  for (int u = 0; u < 8; ++u) {
    float4 t = tb[j0 + u];
    Rq[u] = t.z;
    Sq[u] = t.w;
  }
  float* ab = att + ((long long)(b * 2048 + i0)) * 2048 + j0;
#pragma unroll
  for (int r = 0; r < 4; ++r) {
    float o[8];
#pragma unroll
    for (int u = 0; u < 8; ++u) {
      bool pos = (fi[r] + fj[u]) >= 0.f;
      o[u] = (pos ? En[r] : E2[r]) * (pos ? Rq[u] : Sq[u]);
    }
    float* orow = ab + (long long)r * 2048;
    *(float4*)&orow[0] = make_float4(o[0], o[1], o[2], o[3]);
    *(float4*)&orow[4] = make_float4(o[4], o[5], o[6], o[7]);
  }
}

// ---------------------------------------------------------------------------
// Kernel 5: fp16 MFMA GEMM, BM=176 x BN=256, BK=32, 512 thr = 8 waves
// (2 m-groups of 6/5 frags x 4 q-waves of 64q). B built in-kernel from the
// exp-factor table (no transcendentals, no global B traffic, no att stores).
// Swizzle: the 8 qt-blocks of one (b,ct) share an XCD -> A panel L2-resident.
// ---------------------------------------------------------------------------
__global__ __launch_bounds__(512, 2) void k_gemm(const f16* __restrict__ Apan,
                                                 const float* __restrict__ f,
                                                 const float4* __restrict__ tab4,
                                                 float* __restrict__ out) {
  __shared__ __align__(16) f16 Abuf[2][A_TILE];   // 22528 B
  __shared__ __align__(16) f16 Bbuf[2][8192];     // 32768 B
  __shared__ float fs[2048];                      //  8192 B
  __shared__ __align__(16) float2 Etab[2048];     // 16384 B  (total 79872)

  // swizzle: p bits [2:0]=g&7, [5:3]=qt, [7:6]=g>>3  (g = b*4+ct, 32 groups)
  const int p = blockIdx.x;
  const int g = (p & 7) | ((p >> 6) << 3);
  const int qt = (p >> 3) & 7;
  const int ct = g & 3, b = g >> 2;

  const int tid = threadIdx.x;
  const int w = tid >> 6, lane = tid & 63, qp = lane & 15, gg = lane >> 4;
  const int qw = w & 3, mw = w >> 2;              // q-wave, m-group
  const f16* Ab = Apan + (long long)(b * 4 + ct) * 64 * A_TILE;
  const float* fb = f + b * NN;
  const float4* tb = tab4 + (long long)b * NN;

  // stage f row + (En,E2n) table
  ((float4*)fs)[tid] = ((const float4*)fb)[tid];
#pragma unroll
  for (int i = 0; i < 4; ++i) {
    float4 v = tb[i * 512 + tid];
    Etab[i * 512 + tid] = make_float2(v.x, v.y);
  }

  // per-thread B-column params (q fixed)
  const int qb = tid & 255, kh = tid >> 8;
  const float fq = fb[qt * 256 + qb];
  const float4 myt = tb[qt * 256 + qb];
  const float Rq = myt.z, Sq = myt.w;

  f32x4 acc[6][4];
#pragma unroll
  for (int j = 0; j < 6; ++j)
#pragma unroll
    for (int nf = 0; nf < 4; ++nf) acc[j][nf] = (f32x4){0.f, 0.f, 0.f, 0.f};

  auto stageA = [&](int ks, int bsel) {
    const f16* a = Ab + (long long)ks * A_TILE;
    f16* l = Abuf[bsel];
#pragma unroll
    for (int i = 0; i < 2; ++i) {
      int ch = i * 8 + w;
      if (ch < 11) gl_lds16(a + ch * 512 + lane * 8, l + ch * 512);
    }
  };
  auto buildB = [&](int ks, int bsel) {
    f16* Bs = Bbuf[bsel];
    const int nbase = ks * 32 + kh * 16;
#pragma unroll
    for (int h8 = 0; h8 < 2; ++h8) {
      float4 fA = *(const float4*)&fs[nbase + h8 * 8];
      float4 fB = *(const float4*)&fs[nbase + h8 * 8 + 4];
      const float4* ep = (const float4*)&Etab[nbase + h8 * 8];   // broadcast
      float4 e0 = ep[0], e1 = ep[1], e2 = ep[2], e3 = ep[3];
      float fn[8] = {fA.x, fA.y, fA.z, fA.w, fB.x, fB.y, fB.z, fB.w};
      float Ev[8] = {e0.x, e0.z, e1.x, e1.z, e2.x, e2.z, e3.x, e3.z};
      float E2v[8] = {e0.y, e0.w, e1.y, e1.w, e2.y, e2.w, e3.y, e3.w};
      f16x8 v8;
#pragma unroll
      for (int u = 0; u < 8; ++u) {
        bool pos = (fq + fn[u]) >= 0.f;
        v8[u] = (f16)((pos ? Ev[u] : E2v[u]) * (pos ? Rq : Sq));
      }
      *(f16x8*)&Bs[((kh * 2 + h8) * 256 + qb) * 8] = v8;   // lane-contig 16B
    }
  };
  auto compute = [&](int bsel) {
    const f16* A = Abuf[bsel];
    const f16* Bt = Bbuf[bsel];
    f16x8 bh[4];
#pragma unroll
    for (int nf = 0; nf < 4; ++nf)
      bh[nf] = *(const f16x8*)&Bt[(gg * 256 + qw * 64 + nf * 16 + qp) * 8];
#pragma unroll
    for (int j = 0; j < 6; ++j) {
      if (mw == 0 || j < 5) {                    // wave-uniform guard (6/5 split)
        int mf = mw * 6 + j;
        f16x8 av = *(const f16x8*)&A[(gg * 176 + mf * 16 + qp) * 8];
#pragma unroll
        for (int nf = 0; nf < 4; ++nf)
          acc[j][nf] = __builtin_amdgcn_mfma_f32_16x16x32_f16(av, bh[nf], acc[j][nf], 0, 0, 0);
      }
    }
  };

  // prologue
  stageA(0, 0);
  __syncthreads();     // fs/Etab staged (and A0 drained)
  buildB(0, 0);
  __syncthreads();     // B0 visible

  int cur = 0;
  for (int ks = 0; ks < 63; ++ks) {
    stageA(ks + 1, cur ^ 1);      // async gl_lds into next buffer
    buildB(ks + 1, cur ^ 1);      // VALU only, writes next buffer
    compute(cur);
    __syncthreads();
    cur ^= 1;
  }
  compute(cur);

  // epilogue: C/D layout col(q)=lane&15, row(m)=(lane>>4)*4+r
  float* ob = out + (long long)b * COUT * NN * LL;
#pragma unroll
  for (int j = 0; j < 6; ++j) {
    if (mw == 0 || j < 5) {
      int mf = mw * 6 + j;
#pragma unroll
      for (int r = 0; r < 4; ++r) {
        int m = ct * BM + mf * 16 + gg * 4 + r;
        int c = m / 11, l2 = m - c * 11;
        float* orow = ob + (long long)c * NN * LL + l2;
#pragma unroll
        for (int nf = 0; nf < 4; ++nf) {
          int q = qt * BN + qw * 64 + nf * 16 + qp;
          orow[(long long)q * LL] = acc[j][nf][r];
        }
      }
    }
  }
}

// ---------------------------------------------------------------------------
extern "C" void kernel_launch(void* const* d_in, const int* in_sizes, int n_in,
                              void* d_out, int out_size, void* d_ws, size_t ws_size,
                              hipStream_t stream) {
  const float* x  = (const float*)d_in[0];
  const float* w0 = (const float*)d_in[1];
  const float* b0 = (const float*)d_in[2];
  const float* w1 = (const float*)d_in[3];

  float* fbuf = (float*)d_ws;                                   // 16384 f
  float* maxf = fbuf + BB * NN;                                 // 8 f
  float4* tab4 = (float4*)((char*)d_ws + WS_TAB_OFF);           // 16384 float4
  unsigned int* w0pk_g = (unsigned int*)((char*)d_ws + WS_W0PK_OFF);  // 24 KB
  f16* Apan = (f16*)((char*)d_ws + WS_APAN_OFF);                // 23.07 MB

  float* hp  = (float*)d_out;
  float* att = hp + HP_SIZE;

  k_pack<<<dim3(24), dim3(256), 0, stream>>>(w0, w0pk_g);
  k_conv<<<dim3(BB * 256), dim3(512), 0, stream>>>(x, w0pk_g, b0, w1, Apan, fbuf);
  k_maxf<<<dim3(BB), dim3(256), 0, stream>>>(fbuf, maxf);
  k_rowsum<<<dim3(BB * 512), dim3(256), 0, stream>>>(fbuf, maxf, tab4);
  k_att<<<dim3(BB * 512), dim3(256), 0, stream>>>(fbuf, tab4, att);
  k_gemm<<<dim3(256), dim3(512), 0, stream>>>(Apan, fbuf, tab4, hp);
}

// Round 9
// 173.596 us; speedup vs baseline: 1.0668x; 1.0668x over previous
//
#include <hip/hip_runtime.h>

// Problem constants (fixed by setup_inputs)
#define BB 8
#define CIN 64
#define COUT 64
#define NN 2048
#define TT 13
#define KTT 3
#define LL 11
#define CL 704                         // COUT*LL
#define HP_SIZE 11534336LL             // B*COUT*N*L

// GEMM tiling (32x32x16 MFMA)
#define BM 352                         // 11 m-subtiles of 32
#define BN 128                         // 2 qw x 2 nf x 32
#define A_TILE 11264                   // f16 per BK=32 tile: 2kc x 11msub x 2kh x 32row x 8

// ws layout (bytes): fbuf 65536 | maxf 32 | tab4 262144 | w0pk 24576 | Apan
#define WS_TAB_OFF 65568ULL
#define WS_W0PK_OFF 327712ULL
#define WS_APAN_OFF 352288ULL

typedef _Float16 f16;
typedef __attribute__((ext_vector_type(8))) _Float16 f16x8;
typedef __attribute__((ext_vector_type(2))) _Float16 f16x2;
typedef __attribute__((ext_vector_type(16))) float f32x16;

__device__ __forceinline__ unsigned int pk16(float a, float b) {
  f16 ha = (f16)a, hb = (f16)b;                    // RTN converts
  unsigned short ua = __builtin_bit_cast(unsigned short, ha);
  unsigned short ub = __builtin_bit_cast(unsigned short, hb);
  return (unsigned int)ua | ((unsigned int)ub << 16);
}
__device__ __forceinline__ f16x2 as_h2(unsigned int u) {
  return __builtin_bit_cast(f16x2, u);
}
__device__ __forceinline__ void gl_lds16(const f16* g, f16* l) {
  __builtin_amdgcn_global_load_lds(
      (const __attribute__((address_space(1))) unsigned int*)g,
      (__attribute__((address_space(3))) unsigned int*)l, 16, 0, 0);
}

// ---------------------------------------------------------------------------
// Kernel 0: pack w0 into ci-pair v2f16 form, once.
// ---------------------------------------------------------------------------
__global__ __launch_bounds__(256) void k_pack(const float* __restrict__ w0,
                                              unsigned int* __restrict__ w0pk_g) {
  int tid = blockIdx.x * 256 + threadIdx.x;        // 6144 total
  int c = tid & 63, r = tid >> 6;                  // r = cip*3+kt, 0..95
  int kt = r % 3, cip = r / 3;
  float ev = w0[c * 192 + cip * 6 + kt];
  float od = w0[c * 192 + cip * 6 + 3 + kt];
  w0pk_g[r * 64 + c] = pk16(ev, od);
}

// ---------------------------------------------------------------------------
// Kernel 1: conv0 via v_dot2_f32_f16 -> fp16 A panels (32-row-frag layout) + f.
// A panel: Apan[(b*2+ct)*64+ks][kc2][msub11][kh2][row32][8]  (A_TILE per ks)
// ---------------------------------------------------------------------------
__global__ __launch_bounds__(512, 4) void k_conv(
    const float* __restrict__ x, const unsigned int* __restrict__ w0pk_g,
    const float* __restrict__ b0, const float* __restrict__ w1,
    f16* __restrict__ Apan, float* __restrict__ f) {
  __shared__ unsigned int w0pk[96 * 64];       // 24 KB
  __shared__ unsigned int xspk[32 * 8 * 16];   // 16 KB
  __shared__ f16 As[704 * 10];                 // 14 KB
  const int tid = threadIdx.x;
  const int b = blockIdx.x >> 8;
  const int n0 = (blockIdx.x & 255) << 3;

#pragma unroll
  for (int i = 0; i < 12; ++i) w0pk[i * 512 + tid] = w0pk_g[i * 512 + tid];

#pragma unroll
  for (int i = 0; i < 7; ++i) {
    int task = i * 512 + tid;                  // 3328 total
    if (task < 3328) {
      int cip = task / 104, rem = task - cip * 104;
      long long base = (long long)(b * 64 + 2 * cip) * 26624 + n0 * 13 + rem;
      float ev = x[base];
      float od = x[base + 26624];
      int n = rem / 13, t = rem - n * 13;
      xspk[(cip * 8 + n) * 16 + t] = pk16(ev, od);
    }
  }
  __syncthreads();

  const int c = tid & 63, w = tid >> 6;
  float acc[11];
  const float bias = b0[c];
#pragma unroll
  for (int l = 0; l < 11; ++l) acc[l] = bias;

  for (int cip = 0; cip < 32; ++cip) {
    const unsigned int* xr = &xspk[(cip * 8 + w) * 16];
    uint4 xa = *(const uint4*)xr;
    uint4 xb = *(const uint4*)(xr + 4);
    uint4 xc = *(const uint4*)(xr + 8);
    unsigned int x13[13] = {xa.x, xa.y, xa.z, xa.w, xb.x, xb.y, xb.z, xb.w,
                            xc.x, xc.y, xc.z, xc.w, xr[12]};
    f16x2 wk0 = as_h2(w0pk[(cip * 3 + 0) * 64 + c]);
    f16x2 wk1 = as_h2(w0pk[(cip * 3 + 1) * 64 + c]);
    f16x2 wk2 = as_h2(w0pk[(cip * 3 + 2) * 64 + c]);
#pragma unroll
    for (int l = 0; l < 11; ++l) {
      acc[l] = __builtin_amdgcn_fdot2(as_h2(x13[l]), wk0, acc[l], false);
      acc[l] = __builtin_amdgcn_fdot2(as_h2(x13[l + 1]), wk1, acc[l], false);
      acc[l] = __builtin_amdgcn_fdot2(as_h2(x13[l + 2]), wk2, acc[l], false);
    }
  }

  float p = 0.f;
#pragma unroll
  for (int l = 0; l < 11; ++l) p = fmaf(acc[l], w1[c * 11 + l], p);
#pragma unroll
  for (int off = 32; off; off >>= 1) p += __shfl_xor(p, off, 64);
  if (c == 0) f[b * 2048 + n0 + w] = p;

#pragma unroll
  for (int l = 0; l < 11; ++l) As[(c * 11 + l) * 10 + w] = (f16)acc[l];
  __syncthreads();

  // panel write: this block covers ks, kc=(n0>>4)&1, kh=(n0>>3)&1, kk=0..7
  const int ks = n0 >> 5, kc = (n0 >> 4) & 1, kh = (n0 >> 3) & 1;
  const unsigned int* As32 = (const unsigned int*)As;
#pragma unroll
  for (int i = 0; i < 2; ++i) {
    int m = i * 512 + tid;
    if (m < 704) {
      uint4 v;
      v.x = As32[m * 5 + 0];
      v.y = As32[m * 5 + 1];
      v.z = As32[m * 5 + 2];
      v.w = As32[m * 5 + 3];
      int ct = m / 352, mr = m - ct * 352;
      int msub = mr >> 5, row = m & 31;
      long long base = (long long)((b * 2 + ct) * 64 + ks) * A_TILE +
                       kc * 5632 + msub * 512 + kh * 256 + row * 8;
      *(uint4*)&Apan[base] = v;
    }
  }
}

// ---------------------------------------------------------------------------
// Kernel 2: per-batch max of f
// ---------------------------------------------------------------------------
__global__ __launch_bounds__(256) void k_maxf(const float* __restrict__ f,
                                              float* __restrict__ maxf) {
  const int b = blockIdx.x, tid = threadIdx.x;
  float m = -1e30f;
  for (int i = tid; i < 2048; i += 256) m = fmaxf(m, f[b * 2048 + i]);
#pragma unroll
  for (int off = 32; off; off >>= 1) m = fmaxf(m, __shfl_xor(m, off, 64));
  __shared__ float red[4];
  if ((tid & 63) == 0) red[tid >> 6] = m;
  __syncthreads();
  if (tid == 0) maxf[b] = fmaxf(fmaxf(red[0], red[1]), fmaxf(red[2], red[3]));
}

// ---------------------------------------------------------------------------
// Kernel 3: softmax row sums + exp-factor table tab4 = (En, E2n, Rq, Sq).
// att[n][q] = (fn+fq>=0) ? En_n*Rq_q : E2n_n*Sq_q  (exact factorization)
// ---------------------------------------------------------------------------
__global__ __launch_bounds__(256) void k_rowsum(const float* __restrict__ f,
                                                const float* __restrict__ maxf,
                                                float4* __restrict__ tab4) {
  __shared__ float fs[2048];
  const int b = blockIdx.x >> 9;
  const int q0 = (blockIdx.x & 511) << 2;
  const int tid = threadIdx.x;
#pragma unroll
  for (int i = 0; i < 8; ++i) fs[i * 256 + tid] = f[b * 2048 + i * 256 + tid];
  __syncthreads();
  const int lane = tid & 63, wid = tid >> 6;
  const int q = q0 + wid;
  const float fq = fs[q];
  const float mb = maxf[b];
  float t = fq + mb;
  const float m = t >= 0.f ? t : 0.2f * t;
  float sum = 0.f;
  for (int j = lane; j < 2048; j += 64) {
    float v = fq + fs[j];
    v = v >= 0.f ? v : 0.2f * v;
    sum += __expf(v - m);
  }
#pragma unroll
  for (int off = 32; off; off >>= 1) sum += __shfl_xor(sum, off, 64);
  if (lane == 0) {
    float rq = 1.0f / sum;
    float En = __expf(fq - mb);
    float E2 = __expf(0.2f * fq);
    float Rq = t >= 0.f ? rq : rq * __expf(0.8f * t);
    float Sq = rq * __expf(0.2f * fq - m);
    tab4[b * 2048 + q] = make_float4(En, E2, Rq, Sq);
  }
}

// ---------------------------------------------------------------------------
// Kernel 4: 32x32x16 fp16 MFMA GEMM, B built in-kernel from exp-factor table,
// balanced fused att stores. BM=352, BN=128, BK=32; 512 thr = 8 waves
// (4 mw-groups 3/3/3/2 msub x 2 qw, nf=2). Double-buffered; grid 256 (1/CU).
// Grid mapping: g=(b,ct)=p&15, qt=p>>4 -> same-g blocks share an XCD (p%8).
// ---------------------------------------------------------------------------
__global__ __launch_bounds__(512, 2) void k_gemm(const f16* __restrict__ Apan,
                                                 const float* __restrict__ f,
                                                 const float* __restrict__ maxf,
                                                 const float4* __restrict__ tab4,
                                                 float* __restrict__ att,
                                                 float* __restrict__ out) {
  __shared__ __align__(16) f16 Abuf[2][A_TILE];   // 45056 B
  __shared__ __align__(16) f16 Bbuf[2][4096];     // 16384 B
  __shared__ __align__(16) float2 Etab[2048];     // 16384 B  (total 77824)

  const int p = blockIdx.x;
  const int g = p & 15, qt = p >> 4;
  const int ct = g & 1, b = g >> 1;

  const int tid = threadIdx.x;
  const int w = tid >> 6, lane = tid & 63;
  const int qw = w & 1, mw = w >> 1;              // 2 q-waves x 4 m-groups
  const int l31 = lane & 31, l5 = lane >> 5;
  const int nsub = (mw < 3) ? 3 : 2;              // msub per wave (3/3/3/2)

  const f16* Ab = Apan + (long long)((b * 2 + ct) * 64) * A_TILE;
  const float4* tb = tab4 + (long long)b * NN;

  // stage (En,E2n) table
#pragma unroll
  for (int i = 0; i < 4; ++i) {
    int idx = i * 512 + tid;
    float4 v = tb[idx];
    Etab[idx] = make_float2(v.x, v.y);
  }

  // per-thread B-column params (q fixed for whole kernel)
  const int qb = tid & 127, kg = tid >> 7;        // builder coords
  const float fq = f[b * NN + qt * 128 + qb];
  const float4 qt4 = tb[qt * 128 + qb];
  const float Rq = qt4.z, Sq = qt4.w;
  const float thrE = __expf(-fq - maxf[b]);       // pos <=> En >= thrE

  f32x16 acc[3][2];
#pragma unroll
  for (int j = 0; j < 3; ++j)
#pragma unroll
    for (int nf = 0; nf < 2; ++nf)
#pragma unroll
      for (int z = 0; z < 16; ++z) acc[j][nf][z] = 0.f;

  auto stageA = [&](int ks, int bsel) {
    const f16* a = Ab + (long long)ks * A_TILE;
    f16* l = Abuf[bsel];
#pragma unroll
    for (int i = 0; i < 3; ++i) {
      int ch = i * 512 + tid;                     // 1408 chunks of 16 B
      if (ch < 1408) gl_lds16(a + ch * 8, l + ch * 8);
    }
  };
  auto buildB = [&](int ksn, int bsel) {
    const float4* ep = (const float4*)&Etab[ksn * 32 + kg * 8];   // broadcast
    float4 e0 = ep[0], e1 = ep[1], e2 = ep[2], e3 = ep[3];
    float En[8] = {e0.x, e0.z, e1.x, e1.z, e2.x, e2.z, e3.x, e3.z};
    float E2[8] = {e0.y, e0.w, e1.y, e1.w, e2.y, e2.w, e3.y, e3.w};
    f16x8 v8;
    float vf[8];
#pragma unroll
    for (int u = 0; u < 8; ++u) {
      bool pos = En[u] >= thrE;
      float val = (pos ? En[u] : E2[u]) * (pos ? Rq : Sq);
      vf[u] = val;
      v8[u] = (f16)val;
    }
    *(f16x8*)&Bbuf[bsel][kg * 1024 + qb * 8] = v8;
    if ((ksn >> 5) == ct) {   // balanced fused att: block ct owns n-half
      long long nb = (long long)(b * 2048 + ksn * 32 + kg * 8) * 2048 + qt * 128 + qb;
#pragma unroll
      for (int u = 0; u < 8; ++u) att[nb + (long long)u * 2048] = vf[u];
    }
  };
  auto compute = [&](int bsel) {
    const f16* A = Abuf[bsel];
    const f16* Bt = Bbuf[bsel];
#pragma unroll
    for (int kc = 0; kc < 2; ++kc) {
      f16x8 bv[2];
#pragma unroll
      for (int nf = 0; nf < 2; ++nf)
        bv[nf] = *(const f16x8*)&Bt[kc * 2048 + l5 * 1024 + (qw * 64 + nf * 32 + l31) * 8];
#pragma unroll
      for (int j = 0; j < 3; ++j) {
        if (j < nsub) {                           // wave-uniform
          int ms = mw * 3 + j;
          f16x8 av = *(const f16x8*)&A[kc * 5632 + ms * 512 + l5 * 256 + l31 * 8];
#pragma unroll
          for (int nf = 0; nf < 2; ++nf)
            acc[j][nf] = __builtin_amdgcn_mfma_f32_32x32x16_f16(av, bv[nf], acc[j][nf], 0, 0, 0);
        }
      }
    }
  };

  // prologue
  stageA(0, 0);
  __syncthreads();          // Etab + A0 ready
  buildB(0, 0);
  __syncthreads();          // B0 visible

  int cur = 0;
  for (int ks = 0; ks < 63; ++ks) {
    stageA(ks + 1, cur ^ 1);    // async gl_lds, hides under compute
    compute(cur);
    buildB(ks + 1, cur ^ 1);    // table-driven, no transcendentals
    __syncthreads();
    cur ^= 1;
  }
  compute(cur);

  // epilogue: 32x32 C/D: col(q)=lane&31, row(m)=(reg&3)+8*(reg>>2)+4*(lane>>5)
  float* ob = out + (long long)b * COUT * NN * LL;
#pragma unroll
  for (int j = 0; j < 3; ++j) {
    if (j < nsub) {
#pragma unroll
      for (int rq = 0; rq < 4; ++rq) {
#pragma unroll
        for (int r = 0; r < 4; ++r) {
          int row = r + rq * 8 + l5 * 4;
          int m = ct * BM + (mw * 3 + j) * 32 + row;
          int c = m / 11, l2 = m - c * 11;
#pragma unroll
          for (int nf = 0; nf < 2; ++nf) {
            int q = qt * BN + qw * 64 + nf * 32 + l31;
            ob[((long long)c * NN + q) * LL + l2] = acc[j][nf][rq * 4 + r];
          }
        }
      }
    }
  }
}

// ---------------------------------------------------------------------------
extern "C" void kernel_launch(void* const* d_in, const int* in_sizes, int n_in,
                              void* d_out, int out_size, void* d_ws, size_t ws_size,
                              hipStream_t stream) {
  const float* x  = (const float*)d_in[0];
  const float* w0 = (const float*)d_in[1];
  const float* b0 = (const float*)d_in[2];
  const float* w1 = (const float*)d_in[3];

  float* fbuf = (float*)d_ws;                                   // 16384 f
  float* maxf = fbuf + BB * NN;                                 // 8 f
  float4* tab4 = (float4*)((char*)d_ws + WS_TAB_OFF);           // 16384 float4
  unsigned int* w0pk_g = (unsigned int*)((char*)d_ws + WS_W0PK_OFF);  // 24 KB
  f16* Apan = (f16*)((char*)d_ws + WS_APAN_OFF);                // 23.07 MB

  float* hp  = (float*)d_out;
  float* att = hp + HP_SIZE;

  k_pack<<<dim3(24), dim3(256), 0, stream>>>(w0, w0pk_g);
  k_conv<<<dim3(BB * 256), dim3(512), 0, stream>>>(x, w0pk_g, b0, w1, Apan, fbuf);
  k_maxf<<<dim3(BB), dim3(256), 0, stream>>>(fbuf, maxf);
  k_rowsum<<<dim3(BB * 512), dim3(256), 0, stream>>>(fbuf, maxf, tab4);
  k_gemm<<<dim3(256), dim3(512), 0, stream>>>(Apan, fbuf, maxf, tab4, att, hp);
}